// Round 1
// baseline (427.037 us; speedup 1.0000x reference)
//
#include <hip/hip_runtime.h>

typedef short short8 __attribute__((ext_vector_type(8)));
typedef float f32x4 __attribute__((ext_vector_type(4)));

__device__ __forceinline__ float bf2f(unsigned short u) {
  union { unsigned int i; float f; } v; v.i = ((unsigned int)u) << 16; return v.f;
}
__device__ __forceinline__ unsigned short f2bf(float f) {
  unsigned int x = __float_as_uint(f);
  unsigned int r = (x + 0x7fffu + ((x >> 16) & 1u)) >> 16;  // RNE
  return (unsigned short)r;
}

// ---------------------------------------------------------------------------
// K0: build combined matrices in MFMA B-fragment-friendly layout (bf16).
//   A[k=p][n=g*64+d]   = 0.25 * sum_c Wq[p][16g+c] * Wk[d][16g+c]
//   WVO[k=g*64+d][n=q'] =        sum_c Wv[d][16g+c] * Wout[16g+c][q']
// frag layout: elem(k,n) -> (k>>5)*8192 + n*32 + (k&31)
// ---------------------------------------------------------------------------
__global__ __launch_bounds__(256) void prep_kernel(
    const float* __restrict__ Wq, const float* __restrict__ Wk,
    const float* __restrict__ Wv, const float* __restrict__ Wout,
    unsigned short* __restrict__ Afrag, unsigned short* __restrict__ WVOfrag) {
  const int b = blockIdx.x, tid = threadIdx.x;
  if (b < 256) {
    const int p = b, g = tid >> 6, d = tid & 63;
    float s = 0.f;
#pragma unroll
    for (int c = 0; c < 16; ++c)
      s += Wq[p * 64 + g * 16 + c] * Wk[d * 64 + g * 16 + c];
    s *= 0.25f;  // 1/sqrt(PPG), folded into scores
    const int n = g * 64 + d, k = p;
    Afrag[(size_t)(k >> 5) * 8192 + n * 32 + (k & 31)] = f2bf(s);
  } else {
    const int row = b - 256, g = row >> 6, d = row & 63, q = tid;
    float s = 0.f;
#pragma unroll
    for (int c = 0; c < 16; ++c)
      s += Wv[d * 64 + g * 16 + c] * Wout[(g * 16 + c) * 256 + q];
    WVOfrag[(size_t)(row >> 5) * 8192 + q * 32 + (row & 31)] = f2bf(s);
  }
}

// ---------------------------------------------------------------------------
// K1/K3: C[16384,256] = X[16384,256] @ W[256,256], bf16 MFMA 16x16x32.
// MODE 0: X fp32 (q), out bf16 (qk).  MODE 1: X bf16 (y), out fp32 + bias.
// One WG = 64 rows x 256 cols; 4 waves, wave w owns rows [16w,16w+16).
// ---------------------------------------------------------------------------
template <int MODE>
__global__ __launch_bounds__(256) void gemm256_kernel(
    const void* __restrict__ Xv, const unsigned short* __restrict__ Wfrag,
    void* __restrict__ Outv, const float* __restrict__ bias) {
  __shared__ unsigned short A_s[64 * 40];  // row stride 40 halfwords (pad 8)
  const int tid = threadIdx.x;
  const int m0 = blockIdx.x * 64;
  const int w = tid >> 6, lane = tid & 63;
  const int m_l = lane & 15, quad = lane >> 4;
  const int sm = tid >> 2, skq = tid & 3;  // staging: row, k-chunk

  f32x4 acc[16];
#pragma unroll
  for (int i = 0; i < 16; ++i) acc[i] = (f32x4){0.f, 0.f, 0.f, 0.f};

  for (int ks = 0; ks < 8; ++ks) {
    if (MODE == 0) {
      const float* X = (const float*)Xv;
      const float4* xp =
          (const float4*)(X + (size_t)(m0 + sm) * 256 + ks * 32 + skq * 8);
      float4 x0 = xp[0], x1 = xp[1];
      short8 vv;
      vv[0] = (short)f2bf(x0.x); vv[1] = (short)f2bf(x0.y);
      vv[2] = (short)f2bf(x0.z); vv[3] = (short)f2bf(x0.w);
      vv[4] = (short)f2bf(x1.x); vv[5] = (short)f2bf(x1.y);
      vv[6] = (short)f2bf(x1.z); vv[7] = (short)f2bf(x1.w);
      *(short8*)&A_s[sm * 40 + skq * 8] = vv;
    } else {
      const unsigned short* X = (const unsigned short*)Xv;
      uint4 xv = *(const uint4*)(X + (size_t)(m0 + sm) * 256 + ks * 32 + skq * 8);
      *(uint4*)&A_s[sm * 40 + skq * 8] = xv;
    }
    __syncthreads();
    short8 a = *(const short8*)&A_s[(w * 16 + m_l) * 40 + quad * 8];
#pragma unroll
    for (int nt = 0; nt < 16; ++nt) {
      const unsigned short* bp =
          Wfrag + ((size_t)ks * 256 + nt * 16 + m_l) * 32 + quad * 8;
      short8 bfr = *(const short8*)bp;
      acc[nt] = __builtin_amdgcn_mfma_f32_16x16x32_bf16(a, bfr, acc[nt], 0, 0, 0);
    }
    __syncthreads();
  }
  const int row0 = m0 + w * 16 + quad * 4;  // C/D: col=lane&15, row=quad*4+reg
#pragma unroll
  for (int nt = 0; nt < 16; ++nt) {
    const int col = nt * 16 + m_l;
    if (MODE == 0) {
      unsigned short* Out = (unsigned short*)Outv;
#pragma unroll
      for (int r = 0; r < 4; ++r)
        Out[(size_t)(row0 + r) * 256 + col] = f2bf(acc[nt][r]);
    } else {
      float* Out = (float*)Outv;
      const float bb = bias[col];
#pragma unroll
      for (int r = 0; r < 4; ++r)
        Out[(size_t)(row0 + r) * 256 + col] = acc[nt][r] + bb;
    }
  }
}

// ---------------------------------------------------------------------------
// K2: attention core. One WG per pixel. kv tile (64t x 64d) read once from HBM,
// staged to LDS. scores fp32 -> softmax fp32 -> y = P^T kv fp32 -> bf16 out.
// ---------------------------------------------------------------------------
__global__ __launch_bounds__(256) void attn_kernel(
    const float* __restrict__ kv, const unsigned short* __restrict__ qk,
    unsigned short* __restrict__ yout) {
  __shared__ float kv_s[64 * 68];  // [t][d], row stride 68 (pad 4, 16B-aligned)
  __shared__ float s_lds[4 * 65];  // [g][t], stride 65
  __shared__ float p2[256];        // [t][g] contiguous for b128 broadcast
  __shared__ float yst[64 * 20];   // [d][g*4+tq], stride 20

  const int pixel = blockIdx.x;
  const int tid = threadIdx.x;
  const int t = tid >> 2, q4 = tid & 3;

  const float* kvb =
      kv + ((size_t)(pixel >> 12) << 24) + (size_t)(pixel & 4095) * 64;
  const float4* kp = (const float4*)(kvb + (size_t)t * 262144 + q4 * 16);
  float4 k0 = kp[0], k1 = kp[1], k2 = kp[2], k3 = kp[3];
  float4* ksw = (float4*)&kv_s[t * 68 + q4 * 16];
  ksw[0] = k0; ksw[1] = k1; ksw[2] = k2; ksw[3] = k3;
  const float kvr[16] = {k0.x, k0.y, k0.z, k0.w, k1.x, k1.y, k1.z, k1.w,
                         k2.x, k2.y, k2.z, k2.w, k3.x, k3.y, k3.z, k3.w};

  // scores: s[t,g] = sum_d qk[g,d]*kv[t,d]  (scale already folded into qk)
  const unsigned short* qkb = qk + ((size_t)pixel << 8);
  float sg[4];
#pragma unroll
  for (int g = 0; g < 4; ++g) {
    const uint4* qp = (const uint4*)(qkb + g * 64 + q4 * 16);
    uint4 u0 = qp[0], u1 = qp[1];
    const unsigned int uu[8] = {u0.x, u0.y, u0.z, u0.w, u1.x, u1.y, u1.z, u1.w};
    float acc = 0.f;
#pragma unroll
    for (int i = 0; i < 8; ++i) {
      acc = fmaf(kvr[2 * i],     bf2f((unsigned short)(uu[i] & 0xffffu)), acc);
      acc = fmaf(kvr[2 * i + 1], bf2f((unsigned short)(uu[i] >> 16)),     acc);
    }
    sg[g] = acc;
  }
#pragma unroll
  for (int g = 0; g < 4; ++g) {  // reduce over the 4 d-chunks (lanes xor 1,2)
    float v = sg[g];
    v += __shfl_xor(v, 1);
    v += __shfl_xor(v, 2);
    sg[g] = v;
  }
  s_lds[q4 * 65 + t] = sg[q4];
  __syncthreads();

  // softmax over t: wave g handles group g, lane = t
  {
    const int g = tid >> 6, tt = tid & 63;
    float x = s_lds[g * 65 + tt];
    float m = x;
#pragma unroll
    for (int o = 32; o > 0; o >>= 1) m = fmaxf(m, __shfl_xor(m, o));
    float e = __expf(x - m);
    float ssum = e;
#pragma unroll
    for (int o = 32; o > 0; o >>= 1) ssum += __shfl_xor(ssum, o);
    p2[tt * 4 + g] = e / ssum;
  }
  __syncthreads();

  // y[g,d] = sum_t p[t,g]*kv[t,d]; wave = t-quarter, lane = d
  {
    const int tq = tid >> 6, d = tid & 63;
    float a0 = 0.f, a1 = 0.f, a2 = 0.f, a3 = 0.f;
#pragma unroll
    for (int i = 0; i < 16; ++i) {
      const int t2 = tq * 16 + i;
      const float kvv = kv_s[t2 * 68 + d];
      const float4 pv = *(const float4*)&p2[t2 * 4];  // wave-uniform broadcast
      a0 = fmaf(pv.x, kvv, a0);
      a1 = fmaf(pv.y, kvv, a1);
      a2 = fmaf(pv.z, kvv, a2);
      a3 = fmaf(pv.w, kvv, a3);
    }
    yst[d * 20 + 0 + tq] = a0;
    yst[d * 20 + 4 + tq] = a1;
    yst[d * 20 + 8 + tq] = a2;
    yst[d * 20 + 12 + tq] = a3;
  }
  __syncthreads();

  {
    const int g = tid >> 6, d = tid & 63;
    const float4 v = *(const float4*)&yst[d * 20 + g * 4];
    yout[((size_t)pixel << 8) + g * 64 + d] = f2bf(v.x + v.y + v.z + v.w);
  }
}

// ---------------------------------------------------------------------------
extern "C" void kernel_launch(void* const* d_in, const int* in_sizes, int n_in,
                              void* d_out, int out_size, void* d_ws,
                              size_t ws_size, hipStream_t stream) {
  const float* q    = (const float*)d_in[0];
  const float* kv   = (const float*)d_in[1];
  const float* Wq   = (const float*)d_in[2];
  const float* Wk   = (const float*)d_in[3];
  const float* Wv   = (const float*)d_in[4];
  const float* Wout = (const float*)d_in[5];
  const float* bout = (const float*)d_in[6];

  // workspace (ushort units): A frag 65536 | WVO frag 65536 | qk 4.19M | y 4.19M
  unsigned short* ws      = (unsigned short*)d_ws;
  unsigned short* Afrag   = ws;
  unsigned short* WVOfrag = ws + 65536;
  unsigned short* qk_ws   = ws + 131072;
  unsigned short* y_ws    = ws + 131072 + 4194304;  // total 17,039,360 bytes

  hipLaunchKernelGGL(prep_kernel, dim3(512), dim3(256), 0, stream,
                     Wq, Wk, Wv, Wout, Afrag, WVOfrag);
  hipLaunchKernelGGL((gemm256_kernel<0>), dim3(256), dim3(256), 0, stream,
                     (const void*)q, Afrag, (void*)qk_ws, (const float*)nullptr);
  hipLaunchKernelGGL(attn_kernel, dim3(16384), dim3(256), 0, stream,
                     kv, qk_ws, y_ws);
  hipLaunchKernelGGL((gemm256_kernel<1>), dim3(256), dim3(256), 0, stream,
                     (const void*)y_ws, WVOfrag, d_out, bout);
}

// Round 2
// 422.579 us; speedup vs baseline: 1.0105x; 1.0105x over previous
//
#include <hip/hip_runtime.h>

typedef short short8 __attribute__((ext_vector_type(8)));
typedef short short4v __attribute__((ext_vector_type(4)));
typedef float f32x4 __attribute__((ext_vector_type(4)));

__device__ __forceinline__ float bf2f(unsigned short u) {
  union { unsigned int i; float f; } v; v.i = ((unsigned int)u) << 16; return v.f;
}
__device__ __forceinline__ unsigned short f2bf(float f) {
  unsigned int x = __float_as_uint(f);
  unsigned int r = (x + 0x7fffu + ((x >> 16) & 1u)) >> 16;  // RNE
  return (unsigned short)r;
}

// ---------------------------------------------------------------------------
// K0: build combined matrices in MFMA B-fragment layout (bf16).
//   A[k=p][n=g*64+d]    = 0.25 * sum_c Wq[p][16g+c] * Wk[d][16g+c]
//   WVO[k=g*64+d][n=q'] =        sum_c Wv[d][16g+c] * Wout[16g+c][q']
// frag layout: elem(k,n) -> (k>>5)*8192 + n*32 + (k&31)
// ---------------------------------------------------------------------------
__global__ __launch_bounds__(256) void prep_kernel(
    const float* __restrict__ Wq, const float* __restrict__ Wk,
    const float* __restrict__ Wv, const float* __restrict__ Wout,
    unsigned short* __restrict__ Afrag, unsigned short* __restrict__ WVOfrag) {
  const int b = blockIdx.x, tid = threadIdx.x;
  if (b < 256) {
    const int p = b, g = tid >> 6, d = tid & 63;
    float s = 0.f;
#pragma unroll
    for (int c = 0; c < 16; ++c)
      s += Wq[p * 64 + g * 16 + c] * Wk[d * 64 + g * 16 + c];
    s *= 0.25f;  // 1/sqrt(PPG) folded into scores
    const int n = g * 64 + d, k = p;
    Afrag[(size_t)(k >> 5) * 8192 + n * 32 + (k & 31)] = f2bf(s);
  } else {
    const int row = b - 256, g = row >> 6, d = row & 63, q = tid;
    float s = 0.f;
#pragma unroll
    for (int c = 0; c < 16; ++c)
      s += Wv[d * 64 + g * 16 + c] * Wout[(g * 16 + c) * 256 + q];
    WVOfrag[(size_t)(row >> 5) * 8192 + q * 32 + (row & 31)] = f2bf(s);
  }
}

// ---------------------------------------------------------------------------
// K1/K3: C[16384,256] = X[16384,256] @ W[256,256], bf16 MFMA 16x16x32.
// MODE 0: X fp32 (q), out bf16 (qk).  MODE 1: X bf16 (y), out fp32 + bias.
// 32 rows/WG, grid 512 -> 2 WGs/CU for latency overlap. Wave-pairs:
// waves {0,1} rows 0..15, waves {2,3} rows 16..31; (w&1) picks 8 of 16 nt.
// ---------------------------------------------------------------------------
template <int MODE>
__global__ __launch_bounds__(256) void gemm256_kernel(
    const void* __restrict__ Xv, const unsigned short* __restrict__ Wfrag,
    void* __restrict__ Outv, const float* __restrict__ bias) {
  __shared__ unsigned short A_s[32 * 40];  // 32 rows x 32 k, stride 40 (80B, 16B-mult)
  const int tid = threadIdx.x;
  const int m0 = blockIdx.x * 32;
  const int w = tid >> 6, lane = tid & 63;
  const int m_l = lane & 15, quad = lane >> 4;
  const int nt0 = (w & 1) * 8, m16 = (w >> 1) * 16;
  const int srow = tid >> 3, sc4 = (tid & 7) * 4;  // staging: row, 4-col chunk

  f32x4 acc[8];
#pragma unroll
  for (int i = 0; i < 8; ++i) acc[i] = (f32x4){0.f, 0.f, 0.f, 0.f};

  for (int ks = 0; ks < 8; ++ks) {
    if (MODE == 0) {
      const float* X = (const float*)Xv;
      float4 x = *(const float4*)(X + (size_t)(m0 + srow) * 256 + ks * 32 + sc4);
      short4v vv;
      vv[0] = (short)f2bf(x.x); vv[1] = (short)f2bf(x.y);
      vv[2] = (short)f2bf(x.z); vv[3] = (short)f2bf(x.w);
      *(short4v*)&A_s[srow * 40 + sc4] = vv;
    } else {
      const unsigned short* X = (const unsigned short*)Xv;
      uint2 xv = *(const uint2*)(X + (size_t)(m0 + srow) * 256 + ks * 32 + sc4);
      *(uint2*)&A_s[srow * 40 + sc4] = xv;
    }
    __syncthreads();
    short8 a = *(const short8*)&A_s[(m16 + m_l) * 40 + quad * 8];
#pragma unroll
    for (int j = 0; j < 8; ++j) {
      const unsigned short* bp =
          Wfrag + ((size_t)ks * 256 + (nt0 + j) * 16 + m_l) * 32 + quad * 8;
      short8 bfr = *(const short8*)bp;
      acc[j] = __builtin_amdgcn_mfma_f32_16x16x32_bf16(a, bfr, acc[j], 0, 0, 0);
    }
    __syncthreads();
  }
  const int row0 = m0 + m16 + quad * 4;  // C/D: col=lane&15, row=quad*4+reg
#pragma unroll
  for (int j = 0; j < 8; ++j) {
    const int col = (nt0 + j) * 16 + m_l;
    if (MODE == 0) {
      unsigned short* Out = (unsigned short*)Outv;
#pragma unroll
      for (int r = 0; r < 4; ++r)
        Out[(size_t)(row0 + r) * 256 + col] = f2bf(acc[j][r]);
    } else {
      float* Out = (float*)Outv;
      const float bb = bias[col];
#pragma unroll
      for (int r = 0; r < 4; ++r)
        Out[(size_t)(row0 + r) * 256 + col] = acc[j][r] + bb;
    }
  }
}

// ---------------------------------------------------------------------------
// K2: attention core. One WG per pixel. kv tile (64t x 64d) read once, staged
// to LDS. fp32 scores -> softmax -> y = P^T kv -> bf16 out.
// ---------------------------------------------------------------------------
__global__ __launch_bounds__(256) void attn_kernel(
    const float* __restrict__ kv, const unsigned short* __restrict__ qk,
    unsigned short* __restrict__ yout) {
  __shared__ float kv_s[64 * 68];  // [t][d], stride 68 (bank-rotating, 16B-mult)
  __shared__ float p2[256];        // [t][g]
  __shared__ float yst[64 * 20];   // [d][g*4+tq], stride 20
  float* s_lds = yst;              // [g][t] stride 65 (4*65=260 < 1280) reuse

  const int pixel = blockIdx.x;
  const int tid = threadIdx.x;
  const int t = tid >> 2, q4 = tid & 3;

  // ---- issue ALL global loads up front (qk frags + kv row chunk) ----
  const unsigned short* qkb = qk + ((size_t)pixel << 8);
  uint4 qa[4], qb[4];
#pragma unroll
  for (int g = 0; g < 4; ++g) {
    const uint4* qp = (const uint4*)(qkb + g * 64 + q4 * 16);
    qa[g] = qp[0]; qb[g] = qp[1];
  }
  const float* kvb =
      kv + ((size_t)(pixel >> 12) << 24) + (size_t)(pixel & 4095) * 64;
  const float4* kp = (const float4*)(kvb + (size_t)t * 262144 + q4 * 16);
  float4 k0 = kp[0], k1 = kp[1], k2 = kp[2], k3 = kp[3];

  float4* ksw = (float4*)&kv_s[t * 68 + q4 * 16];
  ksw[0] = k0; ksw[1] = k1; ksw[2] = k2; ksw[3] = k3;
  const float kvr[16] = {k0.x, k0.y, k0.z, k0.w, k1.x, k1.y, k1.z, k1.w,
                         k2.x, k2.y, k2.z, k2.w, k3.x, k3.y, k3.z, k3.w};

  // scores: s[t,g] = sum_d qk[g,d]*kv[t,d]
  float sg[4];
#pragma unroll
  for (int g = 0; g < 4; ++g) {
    const unsigned int uu[8] = {qa[g].x, qa[g].y, qa[g].z, qa[g].w,
                                qb[g].x, qb[g].y, qb[g].z, qb[g].w};
    float acc = 0.f;
#pragma unroll
    for (int i = 0; i < 8; ++i) {
      acc = fmaf(kvr[2 * i],     bf2f((unsigned short)(uu[i] & 0xffffu)), acc);
      acc = fmaf(kvr[2 * i + 1], bf2f((unsigned short)(uu[i] >> 16)),     acc);
    }
    sg[g] = acc;
  }
#pragma unroll
  for (int g = 0; g < 4; ++g) {  // reduce over 4 d-chunks (lanes xor 1,2)
    float v = sg[g];
    v += __shfl_xor(v, 1);
    v += __shfl_xor(v, 2);
    sg[g] = v;
  }
  s_lds[q4 * 65 + t] = sg[q4];
  __syncthreads();

  // softmax over t: wave g handles group g, lane = t
  {
    const int g = tid >> 6, tt = tid & 63;
    float x = s_lds[g * 65 + tt];
    float m = x;
#pragma unroll
    for (int o = 32; o > 0; o >>= 1) m = fmaxf(m, __shfl_xor(m, o));
    float e = __expf(x - m);
    float ssum = e;
#pragma unroll
    for (int o = 32; o > 0; o >>= 1) ssum += __shfl_xor(ssum, o);
    p2[tt * 4 + g] = e / ssum;
  }
  __syncthreads();

  // y[g,d] = sum_t p[t,g]*kv[t,d]; wave = t-quarter, lane = d
  {
    const int tq = tid >> 6, d = tid & 63;
    float a0 = 0.f, a1 = 0.f, a2 = 0.f, a3 = 0.f;
#pragma unroll
    for (int i = 0; i < 16; ++i) {
      const int t2 = tq * 16 + i;
      const float kvv = kv_s[t2 * 68 + d];
      const float4 pv = *(const float4*)&p2[t2 * 4];  // wave-uniform broadcast
      a0 = fmaf(pv.x, kvv, a0);
      a1 = fmaf(pv.y, kvv, a1);
      a2 = fmaf(pv.z, kvv, a2);
      a3 = fmaf(pv.w, kvv, a3);
    }
    __syncthreads();  // s_lds alias of yst: ensure softmax reads done
    yst[d * 20 + 0 + tq] = a0;
    yst[d * 20 + 4 + tq] = a1;
    yst[d * 20 + 8 + tq] = a2;
    yst[d * 20 + 12 + tq] = a3;
  }
  __syncthreads();

  {
    const int g = tid >> 6, d = tid & 63;
    const float4 v = *(const float4*)&yst[d * 20 + g * 4];
    yout[((size_t)pixel << 8) + g * 64 + d] = f2bf(v.x + v.y + v.z + v.w);
  }
}

// ---------------------------------------------------------------------------
extern "C" void kernel_launch(void* const* d_in, const int* in_sizes, int n_in,
                              void* d_out, int out_size, void* d_ws,
                              size_t ws_size, hipStream_t stream) {
  const float* q    = (const float*)d_in[0];
  const float* kv   = (const float*)d_in[1];
  const float* Wq   = (const float*)d_in[2];
  const float* Wk   = (const float*)d_in[3];
  const float* Wv   = (const float*)d_in[4];
  const float* Wout = (const float*)d_in[5];
  const float* bout = (const float*)d_in[6];

  // workspace (ushort units): A frag 65536 | WVO frag 65536 | qk 4.19M | y 4.19M
  unsigned short* ws      = (unsigned short*)d_ws;
  unsigned short* Afrag   = ws;
  unsigned short* WVOfrag = ws + 65536;
  unsigned short* qk_ws   = ws + 131072;
  unsigned short* y_ws    = ws + 131072 + 4194304;

  hipLaunchKernelGGL(prep_kernel, dim3(512), dim3(256), 0, stream,
                     Wq, Wk, Wv, Wout, Afrag, WVOfrag);
  hipLaunchKernelGGL((gemm256_kernel<0>), dim3(512), dim3(256), 0, stream,
                     (const void*)q, Afrag, (void*)qk_ws, (const float*)nullptr);
  hipLaunchKernelGGL(attn_kernel, dim3(16384), dim3(256), 0, stream,
                     kv, qk_ws, y_ws);
  hipLaunchKernelGGL((gemm256_kernel<1>), dim3(512), dim3(256), 0, stream,
                     (const void*)y_ws, WVOfrag, d_out, bout);
}